// Round 1
// baseline (39451.385 us; speedup 1.0000x reference)
//
#include <hip/hip_runtime.h>
#include <hip/hip_bf16.h>

// Problem constants
#define LAYERS 2
#define DIRS   2
#define FEAT   512
#define HDIM   256
#define BATCH  64
#define TLEN   1024
#define FIVEH  1280
#define CHUNK  64          // timesteps per chunk
#define NCHUNK (TLEN / CHUNK)

typedef short bf16x8 __attribute__((ext_vector_type(8)));
typedef float f32x4  __attribute__((ext_vector_type(4)));

__device__ __forceinline__ unsigned short f2bf(float x) {
    unsigned u = __float_as_uint(x);
    unsigned r = (u + 0x7fffu + ((u >> 16) & 1u)) >> 16;
    return (unsigned short)r;
}
__device__ __forceinline__ float bf2f(unsigned short h) {
    return __uint_as_float(((unsigned)h) << 16);
}
__device__ __forceinline__ float sigf(float x) {
    return 1.0f / (1.0f + __expf(-x));
}
__device__ __forceinline__ float tanhfast(float x) {
    // 1 - 2/(e^{2x}+1); exact limits at +-inf
    return 1.0f - 2.0f / (__expf(2.0f * x) + 1.0f);
}

// ---------------------------------------------------------------------------
// Transpose + cast: src fp32 [K][N] (per (l,d) slab) -> dst bf16 [N][K]
// grid: (N/32, K/32, LAYERS*DIRS), block: 256
// ---------------------------------------------------------------------------
__global__ __launch_bounds__(256) void castT_kernel(
    const float* __restrict__ src, unsigned short* __restrict__ dst, int K, int N)
{
    __shared__ float tile[32][33];
    const int n0 = blockIdx.x * 32, k0 = blockIdx.y * 32;
    const size_t slab = (size_t)blockIdx.z * K * N;
    src += slab; dst += slab;
    const int tx = threadIdx.x & 31, ty = threadIdx.x >> 5;  // 32 x 8
    #pragma unroll
    for (int r = 0; r < 32; r += 8)
        tile[ty + r][tx] = src[(size_t)(k0 + ty + r) * N + (n0 + tx)];
    __syncthreads();
    #pragma unroll
    for (int r = 0; r < 32; r += 8)
        dst[(size_t)(n0 + ty + r) * K + (k0 + tx)] = f2bf(tile[tx][ty + r]);
}

// ---------------------------------------------------------------------------
// Projection GEMM for one chunk, both matrices (Wx: N=1280, Wp: N=256 -> 1536)
// A: chunk rows m = t_local*64 + b  (4096 rows), K=512
//   layer 0: features fp32 [B][T][512]; layer 1: x1 bf16 [T][B][512]
// C: gx_c bf16 [d][CHUNK][B][1280] (+bx+bh), px_c bf16 [d][CHUNK][B][256] (+bp)
// grid: (24 n-tiles, 64 m-tiles, 2 dirs), block 256 (4 waves)
// ---------------------------------------------------------------------------
__global__ __launch_bounds__(256) void proj_kernel(
    const float* __restrict__ features,
    const unsigned short* __restrict__ x1,
    const unsigned short* __restrict__ Wx_t,   // [l][d][1280][512] bf16
    const unsigned short* __restrict__ Wp_t,   // [l][d][256][512]  bf16
    const float* __restrict__ bx, const float* __restrict__ bh,
    const float* __restrict__ bp,
    unsigned short* __restrict__ gx_c,
    unsigned short* __restrict__ px_c,
    int layer, int chunk)
{
    const int ntb = blockIdx.x;          // 0..23
    const int mt  = blockIdx.y;          // 0..63
    const int d   = blockIdx.z;
    const int tid = threadIdx.x;
    const int wave = tid >> 6, lane = tid & 63;

    __shared__ __align__(16) unsigned short Alds[64][40];
    __shared__ __align__(16) unsigned short Blds[64][40];

    const int n0 = ntb * 64;             // [0,1536)
    const bool isWx = (n0 < FIVEH);
    const unsigned short* Wt = isWx
        ? (Wx_t + ((size_t)(layer * 2 + d) * FIVEH + n0) * FEAT)
        : (Wp_t + ((size_t)(layer * 2 + d) * HDIM + (n0 - FIVEH)) * FEAT);

    const int m0 = mt * 64;
    const int lm = tid >> 2;             // staging row 0..63
    const int lkb = tid & 3;             // k-block of 8

    // global A row for staging
    const int mrow = m0 + lm;
    const int tl = mrow >> 6;
    const int b  = mrow & 63;
    const int tglob = (d == 0) ? (chunk * CHUNK + tl) : (TLEN - 1 - (chunk * CHUNK + tl));
    const float* Arow0 = features + ((size_t)b * TLEN + tglob) * FEAT;
    const unsigned short* Arow1 = x1 + ((size_t)tglob * BATCH + b) * FEAT;

    f32x4 acc[4];
    #pragma unroll
    for (int i = 0; i < 4; ++i) acc[i] = 0.0f;

    const int fr = lane & 15, quad = lane >> 4;

    for (int k0 = 0; k0 < FEAT; k0 += 32) {
        if (layer == 0) {
            float4 a0 = *(const float4*)(Arow0 + k0 + lkb * 8);
            float4 a1 = *(const float4*)(Arow0 + k0 + lkb * 8 + 4);
            unsigned short* dst = &Alds[lm][lkb * 8];
            dst[0] = f2bf(a0.x); dst[1] = f2bf(a0.y);
            dst[2] = f2bf(a0.z); dst[3] = f2bf(a0.w);
            dst[4] = f2bf(a1.x); dst[5] = f2bf(a1.y);
            dst[6] = f2bf(a1.z); dst[7] = f2bf(a1.w);
        } else {
            uint4 a = *(const uint4*)(Arow1 + k0 + lkb * 8);
            *(uint4*)&Alds[lm][lkb * 8] = a;
        }
        uint4 bv = *(const uint4*)(Wt + (size_t)lm * FEAT + k0 + lkb * 8);
        *(uint4*)&Blds[lm][lkb * 8] = bv;
        __syncthreads();

        bf16x8 af = *(const bf16x8*)&Alds[wave * 16 + fr][quad * 8];
        #pragma unroll
        for (int nt = 0; nt < 4; ++nt) {
            bf16x8 bf = *(const bf16x8*)&Blds[nt * 16 + fr][quad * 8];
            acc[nt] = __builtin_amdgcn_mfma_f32_16x16x32_bf16(af, bf, acc[nt], 0, 0, 0);
        }
        __syncthreads();
    }

    // epilogue: D row = quad*4+reg, col = fr
    const int ldoff = layer * 2 + d;
    #pragma unroll
    for (int nt = 0; nt < 4; ++nt) {
        const int n = n0 + nt * 16 + fr;
        #pragma unroll
        for (int r = 0; r < 4; ++r) {
            const int m2 = m0 + wave * 16 + quad * 4 + r;
            const int tl2 = m2 >> 6, b2 = m2 & 63;
            float v = acc[nt][r];
            if (n < FIVEH) {
                v += bx[(size_t)ldoff * FIVEH + n] + bh[(size_t)ldoff * FIVEH + n];
                gx_c[(((size_t)d * CHUNK + tl2) * BATCH + b2) * FIVEH + n] = f2bf(v);
            } else {
                const int j = n - FIVEH;
                v += bp[(size_t)ldoff * HDIM + j];
                px_c[(((size_t)d * CHUNK + tl2) * BATCH + b2) * HDIM + j] = f2bf(v);
            }
        }
    }
}

// ---------------------------------------------------------------------------
// Recurrence: one workgroup per chain (d,b); 256 threads, thread j owns h-col j.
// Streams Wh_t (bf16 [1280][256]) from L2 each step; h double-buffered in LDS.
// ---------------------------------------------------------------------------
__device__ __forceinline__ void fma8(float& acc, uint4 w, float4 hA, float4 hB) {
    acc = fmaf(__uint_as_float(w.x << 16),          hA.x, acc);
    acc = fmaf(__uint_as_float(w.x & 0xffff0000u),  hA.y, acc);
    acc = fmaf(__uint_as_float(w.y << 16),          hA.z, acc);
    acc = fmaf(__uint_as_float(w.y & 0xffff0000u),  hA.w, acc);
    acc = fmaf(__uint_as_float(w.z << 16),          hB.x, acc);
    acc = fmaf(__uint_as_float(w.z & 0xffff0000u),  hB.y, acc);
    acc = fmaf(__uint_as_float(w.w << 16),          hB.z, acc);
    acc = fmaf(__uint_as_float(w.w & 0xffff0000u),  hB.w, acc);
}

__global__ __launch_bounds__(256) void recur_kernel(
    const unsigned short* __restrict__ gx_c,   // [d][CHUNK][B][1280] bf16
    const unsigned short* __restrict__ px_c,   // [d][CHUNK][B][256]  bf16
    const unsigned short* __restrict__ Wh_t,   // [l][d][1280][256]   bf16
    unsigned short* __restrict__ x1,           // [T][B][512] bf16 (layer0 out)
    float* __restrict__ out,                   // [B][T][512] fp32 (layer1 out)
    float* __restrict__ state,                 // [128][2][256] fp32
    int layer, int chunk)
{
    const int chain = blockIdx.x;    // 0..127
    const int d = chain >> 6, b = chain & 63;
    const int j = threadIdx.x;       // 0..255

    __shared__ float hb[2][HDIM];

    float c_r, h_r;
    if (chunk == 0) { c_r = 0.0f; h_r = 0.0f; }
    else {
        c_r = state[(size_t)chain * 512 + j];
        h_r = state[(size_t)chain * 512 + 256 + j];
    }
    hb[0][j] = h_r;
    __syncthreads();

    const unsigned short* W = Wh_t + (size_t)(layer * 2 + d) * FIVEH * HDIM;
    const unsigned short* Wr0 = W + (size_t)(0 * HDIM + j) * HDIM;
    const unsigned short* Wr1 = W + (size_t)(1 * HDIM + j) * HDIM;
    const unsigned short* Wr2 = W + (size_t)(2 * HDIM + j) * HDIM;
    const unsigned short* Wr3 = W + (size_t)(3 * HDIM + j) * HDIM;
    const unsigned short* Wr4 = W + (size_t)(4 * HDIM + j) * HDIM;

    for (int s = 0; s < CHUNK; ++s) {
        const int cur = s & 1;
        float a0 = 0.f, a1 = 0.f, a2 = 0.f, a3 = 0.f, a4 = 0.f;
        #pragma unroll 4
        for (int kb = 0; kb < 32; ++kb) {
            const float4 hA = *(const float4*)&hb[cur][kb * 8];
            const float4 hB = *(const float4*)&hb[cur][kb * 8 + 4];
            uint4 w0 = *(const uint4*)(Wr0 + kb * 8);
            uint4 w1 = *(const uint4*)(Wr1 + kb * 8);
            uint4 w2 = *(const uint4*)(Wr2 + kb * 8);
            uint4 w3 = *(const uint4*)(Wr3 + kb * 8);
            uint4 w4 = *(const uint4*)(Wr4 + kb * 8);
            fma8(a0, w0, hA, hB);
            fma8(a1, w1, hA, hB);
            fma8(a2, w2, hA, hB);
            fma8(a3, w3, hA, hB);
            fma8(a4, w4, hA, hB);
        }
        const size_t rowb = ((size_t)d * CHUNK + s) * BATCH + b;
        const unsigned short* gx = gx_c + rowb * FIVEH + j;
        const float z0 = a0 + bf2f(gx[0]);
        const float z1 = a1 + bf2f(gx[256]);
        const float z2 = a2 + bf2f(gx[512]);
        const float z3 = a3 + bf2f(gx[768]);
        const float z4 = a4 + bf2f(gx[1024]);
        const float pxv = bf2f(px_c[rowb * HDIM + j]);

        const float ig = sigf(z0);
        const float og = sigf(z1);
        const float fg = sigf(z2);
        const float ug = tanhfast(z3);
        const float rg = sigf(z4);
        c_r = ig * ug + fg * c_r;
        const float hh = og * tanhfast(c_r);
        h_r = rg * hh + (1.0f - rg) * pxv;

        const int tpos = chunk * CHUNK + s;
        const int tglob = d ? (TLEN - 1 - tpos) : tpos;
        if (layer == 0)
            x1[((size_t)tglob * BATCH + b) * 512 + d * HDIM + j] = f2bf(h_r);
        else
            out[((size_t)b * TLEN + tglob) * 512 + d * HDIM + j] = h_r;

        hb[cur ^ 1][j] = h_r;
        __syncthreads();
    }
    state[(size_t)chain * 512 + j] = c_r;
    state[(size_t)chain * 512 + 256 + j] = h_r;
}

// ---------------------------------------------------------------------------
extern "C" void kernel_launch(void* const* d_in, const int* in_sizes, int n_in,
                              void* d_out, int out_size, void* d_ws, size_t ws_size,
                              hipStream_t stream) {
    const float* features = (const float*)d_in[0];
    const float* Wx = (const float*)d_in[1];
    const float* bx = (const float*)d_in[2];
    const float* Wh = (const float*)d_in[3];
    const float* bh = (const float*)d_in[4];
    const float* Wp = (const float*)d_in[5];
    const float* bp = (const float*)d_in[6];
    float* out = (float*)d_out;

    char* ws = (char*)d_ws;
    size_t off = 0;
    auto alloc = [&](size_t bytes) -> void* {
        void* p = ws + off;
        off += (bytes + 255) & ~(size_t)255;
        return p;
    };
    unsigned short* Wx_t = (unsigned short*)alloc((size_t)LAYERS * DIRS * FIVEH * FEAT * 2);
    unsigned short* Wh_t = (unsigned short*)alloc((size_t)LAYERS * DIRS * FIVEH * HDIM * 2);
    unsigned short* Wp_t = (unsigned short*)alloc((size_t)LAYERS * DIRS * HDIM * FEAT * 2);
    unsigned short* x1   = (unsigned short*)alloc((size_t)TLEN * BATCH * 512 * 2);
    unsigned short* gx_c = (unsigned short*)alloc((size_t)DIRS * CHUNK * BATCH * FIVEH * 2);
    unsigned short* px_c = (unsigned short*)alloc((size_t)DIRS * CHUNK * BATCH * HDIM * 2);
    float* state = (float*)alloc((size_t)128 * 512 * 4);

    // one-time (per call) weight transpose+cast
    castT_kernel<<<dim3(FIVEH / 32, FEAT / 32, 4), 256, 0, stream>>>(Wx, Wx_t, FEAT, FIVEH);
    castT_kernel<<<dim3(FIVEH / 32, HDIM / 32, 4), 256, 0, stream>>>(Wh, Wh_t, HDIM, FIVEH);
    castT_kernel<<<dim3(HDIM / 32, FEAT / 32, 4), 256, 0, stream>>>(Wp, Wp_t, FEAT, HDIM);

    for (int l = 0; l < LAYERS; ++l) {
        for (int c = 0; c < NCHUNK; ++c) {
            proj_kernel<<<dim3(24, 64, 2), 256, 0, stream>>>(
                features, x1, Wx_t, Wp_t, bx, bh, bp, gx_c, px_c, l, c);
            recur_kernel<<<128, 256, 0, stream>>>(
                gx_c, px_c, Wh_t, x1, out, state, l, c);
        }
    }
}

// Round 2
// 17607.875 us; speedup vs baseline: 2.2406x; 2.2406x over previous
//
#include <hip/hip_runtime.h>
#include <hip/hip_bf16.h>

// Problem constants
#define LAYERS 2
#define DIRS   2
#define FEAT   512
#define HDIM   256
#define BATCH  64
#define TLEN   1024
#define FIVEH  1280
#define CHUNK  64          // timesteps per chunk
#define NCHUNK (TLEN / CHUNK)
#define NW     8           // workgroups per direction in recurrence

typedef short bf16x8 __attribute__((ext_vector_type(8)));
typedef float f32x4  __attribute__((ext_vector_type(4)));

__device__ __forceinline__ unsigned short f2bf(float x) {
    unsigned u = __float_as_uint(x);
    unsigned r = (u + 0x7fffu + ((u >> 16) & 1u)) >> 16;
    return (unsigned short)r;
}
__device__ __forceinline__ float bf2f(unsigned short h) {
    return __uint_as_float(((unsigned)h) << 16);
}
__device__ __forceinline__ float sigf(float x) {
    return 1.0f / (1.0f + __expf(-x));
}
__device__ __forceinline__ float tanhfast(float x) {
    return 1.0f - 2.0f / (__expf(2.0f * x) + 1.0f);
}

// ---------------------------------------------------------------------------
// Transpose + cast: src fp32 [K][N] (per (l,d) slab) -> dst bf16 [N][K]
// ---------------------------------------------------------------------------
__global__ __launch_bounds__(256) void castT_kernel(
    const float* __restrict__ src, unsigned short* __restrict__ dst, int K, int N)
{
    __shared__ float tile[32][33];
    const int n0 = blockIdx.x * 32, k0 = blockIdx.y * 32;
    const size_t slab = (size_t)blockIdx.z * K * N;
    src += slab; dst += slab;
    const int tx = threadIdx.x & 31, ty = threadIdx.x >> 5;
    #pragma unroll
    for (int r = 0; r < 32; r += 8)
        tile[ty + r][tx] = src[(size_t)(k0 + ty + r) * N + (n0 + tx)];
    __syncthreads();
    #pragma unroll
    for (int r = 0; r < 32; r += 8)
        dst[(size_t)(n0 + ty + r) * K + (k0 + tx)] = f2bf(tile[tx][ty + r]);
}

// ---------------------------------------------------------------------------
// Zero the step flags (re-run every kernel_launch call; ws is poisoned 0xAA)
// ---------------------------------------------------------------------------
__global__ __launch_bounds__(64) void init_kernel(int* __restrict__ flags) {
    if (threadIdx.x < 2 * NW) flags[threadIdx.x * 16] = 0;  // 64B stride per flag
}

// ---------------------------------------------------------------------------
// Projection GEMM for one chunk (Wx: N=1280, Wp: N=256 -> 1536 total columns)
// gx_c layout: [d][CHUNK][5][HDIM][BATCH] bf16 (includes bx+bh)
// px_c layout: [d][CHUNK][HDIM][BATCH]    bf16 (includes bp)
// grid: (24 n-tiles, 64 m-tiles, 2 dirs), block 256 (4 waves)
// ---------------------------------------------------------------------------
__global__ __launch_bounds__(256) void proj_kernel(
    const float* __restrict__ features,
    const unsigned short* __restrict__ x1,
    const unsigned short* __restrict__ Wx_t,   // [l][d][1280][512] bf16
    const unsigned short* __restrict__ Wp_t,   // [l][d][256][512]  bf16
    const float* __restrict__ bx, const float* __restrict__ bh,
    const float* __restrict__ bp,
    unsigned short* __restrict__ gx_c,
    unsigned short* __restrict__ px_c,
    int layer, int chunk)
{
    const int ntb = blockIdx.x;
    const int mt  = blockIdx.y;
    const int d   = blockIdx.z;
    const int tid = threadIdx.x;
    const int wave = tid >> 6, lane = tid & 63;

    __shared__ __align__(16) unsigned short Alds[64][40];
    __shared__ __align__(16) unsigned short Blds[64][40];

    const int n0 = ntb * 64;
    const bool isWx = (n0 < FIVEH);
    const unsigned short* Wt = isWx
        ? (Wx_t + ((size_t)(layer * 2 + d) * FIVEH + n0) * FEAT)
        : (Wp_t + ((size_t)(layer * 2 + d) * HDIM + (n0 - FIVEH)) * FEAT);

    const int m0 = mt * 64;
    const int lm = tid >> 2;
    const int lkb = tid & 3;

    const int mrow = m0 + lm;
    const int tl = mrow >> 6;
    const int b  = mrow & 63;
    const int tglob = (d == 0) ? (chunk * CHUNK + tl) : (TLEN - 1 - (chunk * CHUNK + tl));
    const float* Arow0 = features + ((size_t)b * TLEN + tglob) * FEAT;
    const unsigned short* Arow1 = x1 + ((size_t)tglob * BATCH + b) * FEAT;

    f32x4 acc[4];
    #pragma unroll
    for (int i = 0; i < 4; ++i) acc[i] = 0.0f;

    const int fr = lane & 15, quad = lane >> 4;

    for (int k0 = 0; k0 < FEAT; k0 += 32) {
        if (layer == 0) {
            float4 a0 = *(const float4*)(Arow0 + k0 + lkb * 8);
            float4 a1 = *(const float4*)(Arow0 + k0 + lkb * 8 + 4);
            unsigned short* dst = &Alds[lm][lkb * 8];
            dst[0] = f2bf(a0.x); dst[1] = f2bf(a0.y);
            dst[2] = f2bf(a0.z); dst[3] = f2bf(a0.w);
            dst[4] = f2bf(a1.x); dst[5] = f2bf(a1.y);
            dst[6] = f2bf(a1.z); dst[7] = f2bf(a1.w);
        } else {
            uint4 a = *(const uint4*)(Arow1 + k0 + lkb * 8);
            *(uint4*)&Alds[lm][lkb * 8] = a;
        }
        uint4 bv = *(const uint4*)(Wt + (size_t)lm * FEAT + k0 + lkb * 8);
        *(uint4*)&Blds[lm][lkb * 8] = bv;
        __syncthreads();

        bf16x8 af = *(const bf16x8*)&Alds[wave * 16 + fr][quad * 8];
        #pragma unroll
        for (int nt = 0; nt < 4; ++nt) {
            bf16x8 bf = *(const bf16x8*)&Blds[nt * 16 + fr][quad * 8];
            acc[nt] = __builtin_amdgcn_mfma_f32_16x16x32_bf16(af, bf, acc[nt], 0, 0, 0);
        }
        __syncthreads();
    }

    const int ldoff = layer * 2 + d;
    #pragma unroll
    for (int nt = 0; nt < 4; ++nt) {
        const int n = n0 + nt * 16 + fr;
        #pragma unroll
        for (int r = 0; r < 4; ++r) {
            const int m2 = m0 + wave * 16 + quad * 4 + r;
            const int tl2 = m2 >> 6, b2 = m2 & 63;
            float v = acc[nt][r];
            if (n < FIVEH) {
                v += bx[(size_t)ldoff * FIVEH + n] + bh[(size_t)ldoff * FIVEH + n];
                const int g = n >> 8, j = n & 255;
                gx_c[((((size_t)d * CHUNK + tl2) * 5 + g) * HDIM + j) * BATCH + b2] = f2bf(v);
            } else {
                const int j = n - FIVEH;
                v += bp[(size_t)ldoff * HDIM + j];
                px_c[(((size_t)d * CHUNK + tl2) * HDIM + j) * BATCH + b2] = f2bf(v);
            }
        }
    }
}

// ---------------------------------------------------------------------------
// Recurrence: 16 WGs (8 per direction). WG wg owns j-slice [wg*32, wg*32+32)
// across all 5 gates (160 Wh columns, held in VGPRs). Per step:
//   z[64 x 160] = h[64 x 256] @ Wh_slice   via MFMA 16x16x32
// Wave (mw,jh): m-tiles {2mw,2mw+1}, n-tiles {2g+jh} => gates 0..4 for its
// j-half. All 5 gates for a given (b,j) land in the same lane; c stays in
// VGPRs. h exchanged through parity-double-buffered hbuf + device-scope flags.
// ---------------------------------------------------------------------------
__global__ __launch_bounds__(256, 1) void recur_kernel(
    const unsigned short* __restrict__ gx_c,   // [d][CHUNK][5][256][64] bf16
    const unsigned short* __restrict__ px_c,   // [d][CHUNK][256][64]    bf16
    const unsigned short* __restrict__ Wh_t,   // [l][d][1280][256]      bf16
    unsigned short* __restrict__ x1,           // [T][B][512] bf16
    float* __restrict__ out,                   // [B][T][512] fp32
    float* __restrict__ cbuf,                  // [2][64][256] fp32
    unsigned short* __restrict__ hbuf,         // [2 parity][2 d][64][256] bf16
    int* __restrict__ flags,                   // [2][NW] stride 16 ints
    int layer, int chunk)
{
    const int blk = blockIdx.x;
    const int d = blk >> 3, wg = blk & 7;
    const int tid = threadIdx.x;
    const int wave = tid >> 6, lane = tid & 63;
    const int mw = wave >> 1, jh = wave & 1;
    const int col = lane & 15, quad = lane >> 4;
    const int jg = wg * 32 + jh * 16 + col;   // this lane's j column

    // ---- persistent B fragments: Wh columns for gates 0..4 at column jg ----
    bf16x8 bfr[5][8];
    const unsigned short* Wb = Wh_t + (size_t)(layer * 2 + d) * FIVEH * HDIM;
    #pragma unroll
    for (int g = 0; g < 5; ++g)
        #pragma unroll
        for (int ks = 0; ks < 8; ++ks)
            bfr[g][ks] = *(const bf16x8*)(Wb + (size_t)(g * HDIM + jg) * HDIM + ks * 32 + quad * 8);

    // ---- c state (lane-resident) ----
    float cst[2][4];
    #pragma unroll
    for (int mt = 0; mt < 2; ++mt)
        #pragma unroll
        for (int r = 0; r < 4; ++r) {
            const int b = (2 * mw + mt) * 16 + quad * 4 + r;
            cst[mt][r] = (chunk == 0) ? 0.0f
                       : cbuf[((size_t)d * BATCH + b) * HDIM + jg];
        }

    const int base = layer * TLEN + chunk * CHUNK;   // global step counter base
    int* myflag = &flags[(d * NW + wg) * 16];

    for (int s = 0; s < CHUNK; ++s) {
        const int gs = base + s;

        // ---- wait for h(gs-1) from all WGs in this direction group ----
        if (tid < NW) {
            while (__hip_atomic_load(&flags[(d * NW + tid) * 16],
                                     __ATOMIC_RELAXED, __HIP_MEMORY_SCOPE_AGENT) < gs) { }
        }
        __syncthreads();
        __threadfence();   // acquire: make producers' h-writes visible

        // ---- GEMM: z-slice = h @ Wh_slice ----
        f32x4 acc[2][5];
        #pragma unroll
        for (int mt = 0; mt < 2; ++mt)
            #pragma unroll
            for (int g = 0; g < 5; ++g) acc[mt][g] = 0.0f;

        if ((gs & (TLEN - 1)) != 0) {   // h==0 at the start of each layer
            const unsigned short* hs = hbuf + (size_t)(((gs + 1) & 1) * 2 + d) * BATCH * HDIM;
            bf16x8 af[2][8];
            #pragma unroll
            for (int mt = 0; mt < 2; ++mt)
                #pragma unroll
                for (int ks = 0; ks < 8; ++ks)
                    af[mt][ks] = *(const bf16x8*)(hs + (size_t)((2 * mw + mt) * 16 + col) * HDIM
                                                  + ks * 32 + quad * 8);
            #pragma unroll
            for (int ks = 0; ks < 8; ++ks)
                #pragma unroll
                for (int g = 0; g < 5; ++g) {
                    acc[0][g] = __builtin_amdgcn_mfma_f32_16x16x32_bf16(af[0][ks], bfr[g][ks], acc[0][g], 0, 0, 0);
                    acc[1][g] = __builtin_amdgcn_mfma_f32_16x16x32_bf16(af[1][ks], bfr[g][ks], acc[1][g], 0, 0, 0);
                }
        }

        // ---- gx / px loads (4 consecutive b as one 8B vector) ----
        ushort4 gxv[2][5], pxv[2];
        #pragma unroll
        for (int mt = 0; mt < 2; ++mt) {
            const size_t bb = (2 * mw + mt) * 16 + quad * 4;
            #pragma unroll
            for (int g = 0; g < 5; ++g)
                gxv[mt][g] = *(const ushort4*)(gx_c + ((((size_t)d * CHUNK + s) * 5 + g) * HDIM + jg) * BATCH + bb);
            pxv[mt] = *(const ushort4*)(px_c + (((size_t)d * CHUNK + s) * HDIM + jg) * BATCH + bb);
        }

        const int tpos = chunk * CHUNK + s;
        const int tglob = d ? (TLEN - 1 - tpos) : tpos;
        unsigned short* hdst = hbuf + (size_t)((gs & 1) * 2 + d) * BATCH * HDIM;

        // ---- gate math + h writes ----
        #pragma unroll
        for (int mt = 0; mt < 2; ++mt) {
            const unsigned short* gq0 = (const unsigned short*)&gxv[mt][0];
            const unsigned short* gq1 = (const unsigned short*)&gxv[mt][1];
            const unsigned short* gq2 = (const unsigned short*)&gxv[mt][2];
            const unsigned short* gq3 = (const unsigned short*)&gxv[mt][3];
            const unsigned short* gq4 = (const unsigned short*)&gxv[mt][4];
            const unsigned short* pq  = (const unsigned short*)&pxv[mt];
            #pragma unroll
            for (int r = 0; r < 4; ++r) {
                const float z0 = acc[mt][0][r] + bf2f(gq0[r]);
                const float z1 = acc[mt][1][r] + bf2f(gq1[r]);
                const float z2 = acc[mt][2][r] + bf2f(gq2[r]);
                const float z3 = acc[mt][3][r] + bf2f(gq3[r]);
                const float z4 = acc[mt][4][r] + bf2f(gq4[r]);
                const float p  = bf2f(pq[r]);
                const float ig = sigf(z0);
                const float og = sigf(z1);
                const float fg = sigf(z2);
                const float ug = tanhfast(z3);
                const float rg = sigf(z4);
                const float cc = ig * ug + fg * cst[mt][r];
                cst[mt][r] = cc;
                const float hh = og * tanhfast(cc);
                const float h = rg * hh + (1.0f - rg) * p;
                const int b = (2 * mw + mt) * 16 + quad * 4 + r;
                hdst[(size_t)b * HDIM + jg] = f2bf(h);
                if (layer == 0)
                    x1[((size_t)tglob * BATCH + b) * 512 + d * HDIM + jg] = f2bf(h);
                else
                    out[((size_t)b * TLEN + tglob) * 512 + d * HDIM + jg] = h;
            }
        }

        __syncthreads();          // drains vmcnt for all threads' stores
        if (tid == 0) {
            __threadfence();      // release: writeback so other XCDs see h
            __hip_atomic_store(myflag, gs + 1, __ATOMIC_RELAXED, __HIP_MEMORY_SCOPE_AGENT);
        }
    }

    // ---- persist c for next chunk ----
    #pragma unroll
    for (int mt = 0; mt < 2; ++mt)
        #pragma unroll
        for (int r = 0; r < 4; ++r) {
            const int b = (2 * mw + mt) * 16 + quad * 4 + r;
            cbuf[((size_t)d * BATCH + b) * HDIM + jg] = cst[mt][r];
        }
}

// ---------------------------------------------------------------------------
extern "C" void kernel_launch(void* const* d_in, const int* in_sizes, int n_in,
                              void* d_out, int out_size, void* d_ws, size_t ws_size,
                              hipStream_t stream) {
    const float* features = (const float*)d_in[0];
    const float* Wx = (const float*)d_in[1];
    const float* bx = (const float*)d_in[2];
    const float* Wh = (const float*)d_in[3];
    const float* bh = (const float*)d_in[4];
    const float* Wp = (const float*)d_in[5];
    const float* bp = (const float*)d_in[6];
    float* out = (float*)d_out;

    char* ws = (char*)d_ws;
    size_t off = 0;
    auto alloc = [&](size_t bytes) -> void* {
        void* p = ws + off;
        off += (bytes + 255) & ~(size_t)255;
        return p;
    };
    unsigned short* Wx_t = (unsigned short*)alloc((size_t)LAYERS * DIRS * FIVEH * FEAT * 2);
    unsigned short* Wh_t = (unsigned short*)alloc((size_t)LAYERS * DIRS * FIVEH * HDIM * 2);
    unsigned short* Wp_t = (unsigned short*)alloc((size_t)LAYERS * DIRS * HDIM * FEAT * 2);
    unsigned short* x1   = (unsigned short*)alloc((size_t)TLEN * BATCH * 512 * 2);
    unsigned short* gx_c = (unsigned short*)alloc((size_t)DIRS * CHUNK * BATCH * FIVEH * 2);
    unsigned short* px_c = (unsigned short*)alloc((size_t)DIRS * CHUNK * BATCH * HDIM * 2);
    float* cbuf = (float*)alloc((size_t)DIRS * BATCH * HDIM * 4);
    unsigned short* hbuf = (unsigned short*)alloc((size_t)2 * DIRS * BATCH * HDIM * 2);
    int* flags = (int*)alloc((size_t)2 * NW * 16 * 4);

    init_kernel<<<1, 64, 0, stream>>>(flags);
    castT_kernel<<<dim3(FIVEH / 32, FEAT / 32, 4), 256, 0, stream>>>(Wx, Wx_t, FEAT, FIVEH);
    castT_kernel<<<dim3(FIVEH / 32, HDIM / 32, 4), 256, 0, stream>>>(Wh, Wh_t, HDIM, FIVEH);
    castT_kernel<<<dim3(HDIM / 32, FEAT / 32, 4), 256, 0, stream>>>(Wp, Wp_t, FEAT, HDIM);

    for (int l = 0; l < LAYERS; ++l) {
        for (int c = 0; c < NCHUNK; ++c) {
            proj_kernel<<<dim3(24, 64, 2), 256, 0, stream>>>(
                features, x1, Wx_t, Wp_t, bx, bh, bp, gx_c, px_c, l, c);
            recur_kernel<<<DIRS * NW, 256, 0, stream>>>(
                gx_c, px_c, Wh_t, x1, out, cbuf, hbuf, flags, l, c);
        }
    }
}